// Round 13
// baseline (70.822 us; speedup 1.0000x reference)
//
#include <hip/hip_runtime.h>

// QuantizedConv2d: N=32, CIN=128, H=W=56, COUT=256, 3x3, pad=1 (zp=-3), stride 1.
// Round 13: FUSED staging. pack_x + halo kernels removed; each conv block
// transposes its own 6-row A-halo NCHW->NHWC-int8 directly into LDS
// (16x int4 loads -> byte-pack -> swizzled ds_write_b128; pads filled 0xFD).
// Removes ~12us of serial pre-pass. s_setprio dropped (diagnostic; T5 regime
// evidence says ~0%). Core = r11: 112px x 32cout waves, acc[7][2], (256,3),
// XOR-swizzled LDS-A, B global->reg depth-1 prefetch, ONE barrier.

typedef __attribute__((ext_vector_type(4))) int i32x4;

#define NB_N 32
#define CIN 128
#define HH 56
#define WW 56
#define PH 58                              // padded W (halo row length)
#define COUT 256
#define PIX_PER_IMG (HH*WW)                // 3136
#define X_IMG_INTS (PIX_PER_IMG*CIN)
#define A_BYTES (6*PH*CIN)                 // 44544 (6 halo rows)

// ---------------- pack_w: OIHW int32 -> fragment-ordered int8 ----------------
// frag f = (tap*2 + kb)*16 + nfrag; byte = f*1024 + lane*16 + j
// -> weight[cout = nf*16 + (lane&15)][cin = kb*64 + (lane>>4)*16 + j][kh][kw]
__global__ __launch_bounds__(256) void pack_w_kernel(const int* __restrict__ w,
                                                     signed char* __restrict__ wq) {
    int idx = blockIdx.x * 256 + threadIdx.x;    // 0..18431
    if (idx >= 9 * 2 * 16 * 64) return;
    int lane = idx & 63;
    int fid = idx >> 6;
    int t = fid / 32;
    int rem = fid - t * 32;
    int kb = rem >> 4;
    int nf = rem & 15;
    int cout = nf * 16 + (lane & 15);
    int cinb = kb * 64 + (lane >> 4) * 16;
    int kh = t / 3, kw = t - kh * 3;
    union { signed char b[16]; i32x4 v; } u;
#pragma unroll
    for (int j = 0; j < 16; ++j) {
        int cin = cinb + j;
        u.b[j] = (signed char)w[((cout * CIN + cin) * 3 + kh) * 3 + kw];
    }
    *(i32x4*)(wq + (size_t)idx * 16) = u.v;
}

// ---------------- conv: fused-staging implicit GEMM ----------------
// grid = 1792 blocks: img n (32) x rowblk rb (14, 4 rows) x coutblk cq (4, 64 couts).
// wave (pxhalf, chalf): 112 px (7 m-frags) x 32 couts (2 n-frags); acc[7][2].
__global__ __launch_bounds__(256, 3) void conv_kernel(const int* __restrict__ x,
                                                      const signed char* __restrict__ wq,
                                                      const int* __restrict__ bias,
                                                      const float* __restrict__ wscale,
                                                      int* __restrict__ out) {
    __shared__ __align__(16) signed char lds[A_BYTES];
    const int tid = threadIdx.x;
    const int lane = tid & 63, wv = tid >> 6;
    const int row = lane & 15, grp = lane >> 4;

    // XCD-chunked swizzle: 1792 = 8*224; consecutive 224 blocks (4 images) per XCD.
    int orig = (blockIdx.x & 7) * 224 + (blockIdx.x >> 3);
    int n = orig / 56;
    int rr = orig - n * 56;
    int rb = rr >> 2;          // row-block: output rows [rb*4, rb*4+4)
    int cq = rr & 3;           // cout quarter: [cq*64, +64)
    int pxhalf = wv >> 1, chalf = wv & 1;

    // ---- fused prologue: NCHW int32 -> swizzled NHWC-int8 halo in LDS ----
    // halo pixel pix = r*58 + px (r=0..5, px=0..57), global h = rb*4-1+r, w = px-1.
    // LDS byte d = (pix*128 + c) ^ ((pix&7)<<4).
    const int h0 = rb * 4 - 1;
    // interior: tasks (r, wq4, co): 16 channels x 4 widths -> 4 swizzled b128 writes
    for (int task = tid; task < 672; task += 256) {
        int r = task / 112;            // 0..5
        int rem = task - r * 112;
        int wq4 = rem >> 3;            // w-quad 0..13
        int co = rem & 7;              // channel octet (16 ch)
        int h = h0 + r;
        if ((unsigned)h < (unsigned)HH) {
            const int* src = x + ((size_t)n * CIN + co * 16) * PIX_PER_IMG + h * WW + wq4 * 4;
            int wds[4][4] = {{0,0,0,0},{0,0,0,0},{0,0,0,0},{0,0,0,0}};
#pragma unroll
            for (int k = 0; k < 16; ++k) {
                i32x4 v = *(const i32x4*)(src + k * PIX_PER_IMG);
#pragma unroll
                for (int j = 0; j < 4; ++j)
                    wds[j][k >> 2] |= (v[j] & 255) << ((k & 3) * 8);
            }
#pragma unroll
            for (int j = 0; j < 4; ++j) {
                int pix = r * PH + (wq4 * 4 + j + 1);
                int d = ((pix << 7) + co * 16) ^ ((pix & 7) << 4);
                i32x4 wv4 = {wds[j][0], wds[j][1], wds[j][2], wds[j][3]};
                *(i32x4*)(lds + d) = wv4;
            }
        }
    }
    // pads: row-pads (h out of range) + col-pads (px 0 and 57) -> 0xFD
    {
        const i32x4 pad = {(int)0xFDFDFDFD, (int)0xFDFDFDFD, (int)0xFDFDFDFD, (int)0xFDFDFDFD};
        for (int t = tid; t < 6 * PH; t += 256) {
            int r = t / PH, px = t - r * PH;
            int h = h0 + r, w = px - 1;
            if (!(((unsigned)h < (unsigned)HH) && ((unsigned)w < (unsigned)WW))) {
#pragma unroll
                for (int co = 0; co < 8; ++co) {
                    int d = ((t << 7) + co * 16) ^ ((t & 7) << 4);
                    *(i32x4*)(lds + d) = pad;
                }
            }
        }
    }
    __syncthreads();   // the ONLY barrier

    // per-m center pixel index in halo (padded coords, rows 0..5 of halo)
    int pc[7];
#pragma unroll
    for (int m = 0; m < 7; ++m) {
        int off = pxhalf * 112 + m * 16 + row;               // 0..223
        int lr = (off >= 56) + (off >= 112) + (off >= 168);  // off/56
        int w = off - lr * 56;
        pc[m] = (lr + 1) * PH + (w + 1);
    }

    const int tapd[9] = {-PH - 1, -PH, -PH + 1, -1, 0, 1, PH - 1, PH, PH + 1};

    // B direct from global (fragment-ordered, L2-resident), 1-step prefetch.
    // Wave's 2 n-frags: nf = cq*4 + chalf*2 + {0,1}.  Step stride = 16KB.
    const signed char* wbase = wq + (size_t)(cq * 4 + chalf * 2) * 1024 + lane * 16;

    i32x4 acc[7][2] = {};
    i32x4 bn0 = *(const i32x4*)(wbase);
    i32x4 bn1 = *(const i32x4*)(wbase + 1024);

#pragma unroll
    for (int s = 0; s < 18; ++s) {
        const int t = s >> 1, kb = s & 1;
        i32x4 b0 = bn0, b1 = bn1;
        if (s < 17) {   // prefetch next step's B fragments (hidden under 14 MFMAs)
            bn0 = *(const i32x4*)(wbase + (s + 1) * 16384);
            bn1 = *(const i32x4*)(wbase + (s + 1) * 16384 + 1024);
        }
        // A ds_reads (swizzled)
        i32x4 a[7];
#pragma unroll
        for (int m = 0; m < 7; ++m) {
            int pix = pc[m] + tapd[t];
            int g = (pix << 7) + (kb << 6) + (grp << 4);
            int d = g ^ ((pix & 7) << 4);
            a[m] = *(const i32x4*)(lds + d);
        }
#pragma unroll
        for (int m = 0; m < 7; ++m) {
            acc[m][0] = __builtin_amdgcn_mfma_i32_16x16x64_i8(a[m], b0, acc[m][0], 0, 0, 0);
            acc[m][1] = __builtin_amdgcn_mfma_i32_16x16x64_i8(a[m], b1, acc[m][1], 0, 0, 0);
        }
    }

    // ---- epilogue: acc + 2*bias -> scale -> rint -> clamp -> int32 store ----
    float sc[2];
    int b2[2];
    const int coutbase = cq * 64 + chalf * 32;
#pragma unroll
    for (int j = 0; j < 2; ++j) {
        int cout = coutbase + j * 16 + row;
        sc[j] = wscale[cout] * 0.5f;          // 0.05/0.1 * ws
        b2[j] = 2 * bias[cout];
    }
    const int pixbase = rb * 224 + pxhalf * 112;
#pragma unroll
    for (int m = 0; m < 7; ++m) {
        int pl = pixbase + m * 16 + grp * 4;  // pixel of reg 0
        size_t obase = (size_t)n * (COUT * PIX_PER_IMG) + pl;
#pragma unroll
        for (int j = 0; j < 2; ++j) {
            int cout = coutbase + j * 16 + row;
            i32x4 v;
#pragma unroll
            for (int r = 0; r < 4; ++r) {
                int o = acc[m][j][r] + b2[j];
                float f = fmaf((float)o, sc[j], 5.0f);
                f = rintf(f);                 // RNE == jnp.round
                f = fminf(fmaxf(f, -128.0f), 127.0f);
                v[r] = (int)f;
            }
            *(i32x4*)(out + obase + (size_t)cout * PIX_PER_IMG) = v;
        }
    }
}

extern "C" void kernel_launch(void* const* d_in, const int* in_sizes, int n_in,
                              void* d_out, int out_size, void* d_ws, size_t ws_size,
                              hipStream_t stream) {
    const int* x = (const int*)d_in[0];
    const int* w = (const int*)d_in[1];
    const int* bias = (const int*)d_in[2];
    const float* ws = (const float*)d_in[3];
    int* out = (int*)d_out;

    signed char* wq = (signed char*)d_ws;      // 288 KB fragment-ordered weights

    pack_w_kernel<<<72, 256, 0, stream>>>(w, wq);
    conv_kernel<<<1792, 256, 0, stream>>>(x, wq, bias, ws, out);
}